// Round 1
// baseline (238.393 us; speedup 1.0000x reference)
//
#include <hip/hip_runtime.h>

// TrainablePCEN: x[B=64,F=128,T=4000] f32; EMA along T then pointwise pow ops.
// One block per (b,f) row; affine-map parallel scan for the IIR.

#define LOG2F(v) __builtin_amdgcn_logf(v)   // hardware log2
#define EXP2F(v) __builtin_amdgcn_exp2f(v)  // hardware 2^x

constexpr int   T_LEN = 4000;
constexpr int   F_DIM = 128;
constexpr int   EPT   = 16;            // elements per thread
constexpr int   TPB   = 256;           // 250 active (250*16 = 4000)
constexpr int   ACTIVE = T_LEN / EPT;  // 250
constexpr float S_C   = 0.025f;
constexpr float A1    = 1.0f - S_C;    // 0.975
constexpr float EPS_C = 1e-6f;

constexpr float pow_n(double a, int n) {
    double r = 1.0;
    for (int i = 0; i < n; ++i) r *= a;
    return (float)r;
}
constexpr float A16 = pow_n((double)A1, EPT);  // 0.975^16

__global__ __launch_bounds__(TPB) void pcen_kernel(
    const float* __restrict__ x,
    const float* __restrict__ log_gain,
    const float* __restrict__ log_bias,
    const float* __restrict__ log_power,
    float* __restrict__ out)
{
    const int row  = blockIdx.x;           // b*F + f
    const int f    = row & (F_DIM - 1);
    const long long base = (long long)row * T_LEN;
    const int tid  = threadIdx.x;
    const int lane = tid & 63;
    const int wid  = tid >> 6;
    const bool active = tid < ACTIVE;

    // per-row scalars (uniform within block)
    const float g  = expf(log_gain[f]);
    const float b  = expf(log_bias[f]);
    const float p  = expf(log_power[f]);
    const float bp = EXP2F(p * LOG2F(b));  // same path as output -> x=0 gives exact 0

    // ---- load 16 contiguous elems into registers (float4 x4, 16B aligned) ----
    float xv[EPT];
    const float4* xin = reinterpret_cast<const float4*>(x + base) + tid * 4;
    if (active) {
        #pragma unroll
        for (int q = 0; q < 4; ++q) {
            float4 v = xin[q];
            xv[q*4 + 0] = v.x; xv[q*4 + 1] = v.y;
            xv[q*4 + 2] = v.z; xv[q*4 + 3] = v.w;
        }
    }

    // ---- thread-local affine map: m -> Ai*m + Bi over its 16 elems ----
    float Bi = 0.0f;
    if (active) {
        #pragma unroll
        for (int j = 0; j < EPT; ++j) Bi = fmaf(A1, Bi, S_C * xv[j]);
    }
    float Ai = active ? A16 : 1.0f;

    // ---- wave-level inclusive scan (compose: later ∘ earlier) ----
    #pragma unroll
    for (int d = 1; d < 64; d <<= 1) {
        float Ap = __shfl_up(Ai, d);
        float Bp = __shfl_up(Bi, d);
        if (lane >= d) { Bi = fmaf(Ai, Bp, Bi); Ai *= Ap; }
    }

    __shared__ float sA[4], sB[4], sM0;
    if (lane == 63) { sA[wid] = Ai; sB[wid] = Bi; }
    if (tid == 0)   { sM0 = xv[0]; }   // m_{-1} = x_0  (then m_0 = 0.975*x0 + 0.025*x0)
    __syncthreads();

    // compose aggregates of previous waves (identity for wave 0)
    float pA = 1.0f, pB = 0.0f;
    for (int w = 0; w < wid; ++w) { pB = fmaf(sA[w], pB, sB[w]); pA *= sA[w]; }

    // wave-exclusive from inclusive
    float eA = __shfl_up(Ai, 1);
    float eB = __shfl_up(Bi, 1);
    if (lane == 0) { eA = 1.0f; eB = 0.0f; }

    // m entering this thread's chunk: eA*(pA*m0 + pB) + eB
    float m = fmaf(eA, fmaf(pA, sM0, pB), eB);

    // ---- replay 16 elems, compute output, store float4 x4 ----
    if (active) {
        float4* o4 = reinterpret_cast<float4*>(out + base) + tid * 4;
        #pragma unroll
        for (int q = 0; q < 4; ++q) {
            float4 o;
            float ov[4];
            #pragma unroll
            for (int j = 0; j < 4; ++j) {
                const float xj = xv[q*4 + j];
                m = fmaf(A1, m, S_C * xj);
                // v = x * (m+eps)^(-g)
                float v = xj * EXP2F(-g * LOG2F(m + EPS_C));
                // out = (v+b)^p - b^p
                ov[j] = EXP2F(p * LOG2F(v + b)) - bp;
            }
            o.x = ov[0]; o.y = ov[1]; o.z = ov[2]; o.w = ov[3];
            o4[q] = o;
        }
    }
}

extern "C" void kernel_launch(void* const* d_in, const int* in_sizes, int n_in,
                              void* d_out, int out_size, void* d_ws, size_t ws_size,
                              hipStream_t stream) {
    const float* x  = (const float*)d_in[0];
    const float* lg = (const float*)d_in[1];
    const float* lb = (const float*)d_in[2];
    const float* lp = (const float*)d_in[3];
    float* out = (float*)d_out;

    const int rows = in_sizes[0] / T_LEN;  // B*F = 8192
    pcen_kernel<<<dim3(rows), dim3(TPB), 0, stream>>>(x, lg, lb, lp, out);
}

// Round 5
// 227.832 us; speedup vs baseline: 1.0464x; 1.0464x over previous
//
#include <hip/hip_runtime.h>

// TrainablePCEN: x[B=64,F=128,T=4000] f32; EMA along T then pointwise pow ops.
// One block per (b,f) row. EPT=4 so lane i loads/stores float4 i -> fully
// coalesced (R1's EPT=16 made every wave instr touch 64 distinct lines).

#define LOG2F(v) __builtin_amdgcn_logf(v)   // hardware log2
#define EXP2F(v) __builtin_amdgcn_exp2f(v)  // hardware 2^x

constexpr int   T_LEN  = 4000;
constexpr int   F_DIM  = 128;
constexpr int   TPB    = 1024;           // 16 waves
constexpr int   ACTIVE = T_LEN / 4;      // 1000 threads carry one float4 each
constexpr float S_C    = 0.025f;
constexpr float A1     = 1.0f - S_C;     // 0.975
constexpr float EPS_C  = 1e-6f;
constexpr float A4     = A1 * A1 * A1 * A1;

__global__ __launch_bounds__(TPB) void pcen_kernel(
    const float* __restrict__ x,
    const float* __restrict__ log_gain,
    const float* __restrict__ log_bias,
    const float* __restrict__ log_power,
    float* __restrict__ out)
{
    const int row  = blockIdx.x;            // b*F + f
    const int f    = row & (F_DIM - 1);
    const long long base = (long long)row * T_LEN;
    const int tid  = threadIdx.x;
    const int lane = tid & 63;
    const int wid  = tid >> 6;
    const bool act = tid < ACTIVE;

    // per-row scalars (uniform within block)
    const float g  = expf(log_gain[f]);
    const float b  = expf(log_bias[f]);
    const float p  = expf(log_power[f]);
    const float bp = EXP2F(p * LOG2F(b));   // same path as output -> x=0 gives exact 0

    // ---- coalesced load: lane i reads float4 i ----
    float4 xv = make_float4(0.f, 0.f, 0.f, 0.f);
    if (act) xv = reinterpret_cast<const float4*>(x + base)[tid];

    // ---- thread-local affine map over 4 elems: m -> Ai*m + Bi ----
    float Bi = 0.0f;
    if (act) {
        Bi = S_C * xv.x;
        Bi = fmaf(A1, Bi, S_C * xv.y);
        Bi = fmaf(A1, Bi, S_C * xv.z);
        Bi = fmaf(A1, Bi, S_C * xv.w);
    }
    float Ai = act ? A4 : 1.0f;

    // ---- wave-level inclusive scan (compose: later ∘ earlier) ----
    #pragma unroll
    for (int d = 1; d < 64; d <<= 1) {
        float Ap = __shfl_up(Ai, d);
        float Bp = __shfl_up(Bi, d);
        if (lane >= d) { Bi = fmaf(Ai, Bp, Bi); Ai *= Ap; }
    }

    __shared__ float sA[16], sB[16], sPA[16], sPB[16], sM0;
    if (lane == 63) { sA[wid] = Ai; sB[wid] = Bi; }
    if (tid == 0)   { sM0 = xv.x; }          // m_{-1} = x_0  (=> m_0 = x_0)
    __syncthreads();

    // ---- wave 0, lanes 0..15: mini-scan over the 16 wave aggregates ----
    if (wid == 0 && lane < 16) {
        float a  = sA[lane];
        float bb = sB[lane];
        #pragma unroll
        for (int d = 1; d < 16; d <<= 1) {
            float ap = __shfl_up(a, d);
            float bpp = __shfl_up(bb, d);
            if (lane >= d) { bb = fmaf(a, bpp, bb); a *= ap; }
        }
        float ea = __shfl_up(a, 1);
        float eb = __shfl_up(bb, 1);
        if (lane == 0) { ea = 1.0f; eb = 0.0f; }
        sPA[lane] = ea;                      // exclusive prefix of waves [0..lane)
        sPB[lane] = eb;
    }
    __syncthreads();

    // ---- m entering this thread's chunk ----
    const float pA = sPA[wid];
    const float pB = sPB[wid];
    float eA = __shfl_up(Ai, 1);
    float eB = __shfl_up(Bi, 1);
    if (lane == 0) { eA = 1.0f; eB = 0.0f; }
    float m = fmaf(eA, fmaf(pA, sM0, pB), eB);

    // ---- compute 4 outputs, coalesced float4 store ----
    if (act) {
        float xs[4] = { xv.x, xv.y, xv.z, xv.w };
        float ov[4];
        #pragma unroll
        for (int j = 0; j < 4; ++j) {
            m = fmaf(A1, m, S_C * xs[j]);
            float v = xs[j] * EXP2F(-g * LOG2F(m + EPS_C));   // x / (m+eps)^g
            ov[j]   = EXP2F(p * LOG2F(v + b)) - bp;           // (v+b)^p - b^p
        }
        float4 o = make_float4(ov[0], ov[1], ov[2], ov[3]);
        reinterpret_cast<float4*>(out + base)[tid] = o;
    }
}

extern "C" void kernel_launch(void* const* d_in, const int* in_sizes, int n_in,
                              void* d_out, int out_size, void* d_ws, size_t ws_size,
                              hipStream_t stream) {
    const float* x  = (const float*)d_in[0];
    const float* lg = (const float*)d_in[1];
    const float* lb = (const float*)d_in[2];
    const float* lp = (const float*)d_in[3];
    float* out = (float*)d_out;

    const int rows = in_sizes[0] / T_LEN;   // B*F = 8192
    pcen_kernel<<<dim3(rows), dim3(TPB), 0, stream>>>(x, lg, lb, lp, out);
}